// Round 9
// baseline (87.543 us; speedup 1.0000x reference)
//
#include <hip/hip_runtime.h>
#include <math.h>

#define K_SIZE 5
#define EPS    1e-6f
#define EPS_L  1e-3f
#define EPS_W  1e-3f

#define BATCH 4
#define HGT   512
#define WID   512
#define HW    (HGT * WID)

// fp16 quad table: entry[b][ri][k] (ri,k in 0..512) =
//   { img[ri-1][k-1], img[ri-1][k], img[ri][k-1], img[ri][k] }  (OOB halves = 0)
// ri = y0+1, k = x0+1. One 8B load -> all 4 bilinear corners.
#define ENT        513
#define ROW_ENTRIES 520                         // pad for 64B-aligned rows
#define ROW_BYTES  (ROW_ENTRIES * 8)            // 4160 = 64*65
#define IMG_BYTES  (ENT * ROW_BYTES)            // 2,134,080
#define TBL_BYTES  ((size_t)BATCH * IMG_BYTES)  // ~8.5 MB

typedef int int32x4 __attribute__((ext_vector_type(4)));
typedef float floatx2 __attribute__((ext_vector_type(2)));
typedef _Float16 half4v __attribute__((ext_vector_type(4)));

// Raw buffer loads with hardware bounds check: OOB -> returns 0
__device__ float llvm_amdgcn_raw_buffer_load_fp32(int32x4 srsrc, int voffset,
                                                  int soffset, int aux)
    __asm("llvm.amdgcn.raw.buffer.load.f32");
__device__ floatx2 llvm_amdgcn_raw_buffer_load_2fp32(int32x4 srsrc, int voffset,
                                                     int soffset, int aux)
    __asm("llvm.amdgcn.raw.buffer.load.v2f32");

// ---------------- pack: f32 image -> fp16 quad table ----------------
__global__ __launch_bounds__(256) void pack_kernel(
    const float* __restrict__ input, char* __restrict__ tbl)
{
    const int t = blockIdx.x * blockDim.x + threadIdx.x;
    if (t >= BATCH * ENT * ENT) return;
    const int k  = t % ENT;
    const int ri = (t / ENT) % ENT;
    const int b  = t / (ENT * ENT);

    const float* __restrict__ img = input + (size_t)b * HW;

    const bool top = (ri >= 1), bot = (ri <= HGT - 1);
    const bool lef = (k  >= 1), rig = (k  <= WID - 1);
    const int yT = (ri - 1) << 9;
    const int yB = ri << 9;

    union { half4v h; floatx2 f; } cv;
    cv.h.x = (_Float16)((top && lef) ? img[yT + k - 1] : 0.0f);
    cv.h.y = (_Float16)((top && rig) ? img[yT + k]     : 0.0f);
    cv.h.z = (_Float16)((bot && lef) ? img[yB + k - 1] : 0.0f);
    cv.h.w = (_Float16)((bot && rig) ? img[yB + k]     : 0.0f);

    floatx2* dst = (floatx2*)(tbl + (size_t)b * IMG_BYTES + (size_t)ri * ROW_BYTES + ((size_t)k << 3));
    *dst = cv.f;
}

// ---------------- main fused kernel (fp16 quad-table gather + cell dedup) ----
__global__ __launch_bounds__(256) void fused_sample_kernel_f16(
    const char* __restrict__ tbl,      // packed table in ws
    const float* __restrict__ Lp,      // (B,H,W,3)
    const float* __restrict__ wbuf,    // (B,2,H,W)
    float* __restrict__ out)           // (B,1,H,W)
{
#pragma clang fp contract(off)
    const int idx = blockIdx.x * blockDim.x + threadIdx.x;

    const int b = blockIdx.x >> 10;     // 1024 blocks per image (uniform per block)
    const int p = idx & (HW - 1);
    const int y = p >> 9;
    const int x = p & (WID - 1);

    // SRD over this image's table: OOB rows -> outside num_records -> 0.
    union {
        struct { const void* base; unsigned num; unsigned cfg; } s;
        int32x4 v;
    } desc;
    desc.s.base = (const void*)(tbl + (size_t)b * IMG_BYTES);
    desc.s.num  = (unsigned)IMG_BYTES;
    desc.s.cfg  = 0x00020000u;
    const int32x4 rsrc = desc.v;

    // ---- per-pixel matrix (exactly mirrors numpy op order; amplified path) ----
    const size_t l_off = (size_t)idx * 3;
    const float L0 = Lp[l_off + 0];
    const float L1 = Lp[l_off + 1];
    const float L2 = Lp[l_off + 2];

    const float a  = fabsf(L0) + EPS_L;
    const float bb = L1;
    const float c  = fabsf(L2) + EPS_L;

    const float M00 = a * a;
    const float M01 = a * bb;
    const float M11 = (bb * bb) + (c * c);

    const float d00 = M00 + EPS;
    const float d11 = M11 + EPS;
    const float det = (d00 * d11) - (M01 * M01);
    const float I00 = d11 / det;          // IEEE f32 div, same as np
    const float I01 = (-M01) / det;
    const float I11 = d00 / det;

    const float wx = wbuf[(size_t)b * 2 * HW + p];
    const float wy = wbuf[(size_t)b * 2 * HW + HW + p];

    const float q    = (((I00 * wx) * wx) + (((2.0f * I01) * wx) * wy)) + ((I11 * wy) * wy);
    const float norm = sqrtf(q + EPS);

    const float e    = (float)exp((double)(-norm));   // correctly-rounded f32 exp
    const float sig  = 1.0f / (1.0f + e);
    const float tuned = ((sig - 0.5f) * 2.0f) * (1.0f - EPS_W);
    const float scale = tuned / (norm + EPS);         // IEEE div
    const float wtx = wx * scale;
    const float wty = wy * scale;

    // cos/sin of the FLOAT32-ROUNDED theta_k
    const float CT[K_SIZE] = { 1.0f,  0.30901696090f, -0.80901703575f, -0.80901693229f,  0.30901712828f };
    const float ST[K_SIZE] = { 0.0f,  0.95105652717f,  0.58778519534f, -0.58778533774f, -0.95105647279f };
    const float SV[K_SIZE] = { 0.2f, 0.4f, 0.6f, 0.8f, 1.0f };

    const float fy = (float)y;
    const float fx = (float)x;

    float acc0 = 0.0f;
    float acc1 = 0.0f;

    // dedup state: reuse the quad when the sample stays in the same cell.
    // Exact optimization: identical offset -> identical values.
    unsigned prevOff = 0xFFFFFFFFu;     // never a valid offset (> IMG_BYTES)
    floatx2 pf = {0.0f, 0.0f};

    #pragma unroll
    for (int k = 0; k < K_SIZE; ++k) {
        const float ct = CT[k];
        const float st = ST[k];
        // amplified path: keep exact left-assoc, no contraction
        const float quad = (((M00 * ct) * ct) + (((2.0f * M01) * ct) * st)) + ((M11 * st) * st);
        const float F    = (sqrtf(quad) + (wtx * ct)) + (wty * st);
        const float Fe   = F + EPS;
        // downstream of cancellation: approx rcp safe (position error ~1e-7 rel)
        const float rFe  = __builtin_amdgcn_rcpf(Fe);
        const float yx   = ct * rFe;
        const float yy   = st * rFe;

        #pragma unroll
        for (int s = 0; s < K_SIZE; ++s) {
            const float sv = SV[s];
            const float gy = fmaf(sv, yy, fy);
            const float gx = fmaf(sv, yx, fx);

            const int   y0i = (int)floorf(gy);      // v_cvt_flr_i32_f32
            const int   x0i = (int)floorf(gx);
            const float wyf = __builtin_amdgcn_fractf(gy);
            const float wxf = __builtin_amdgcn_fractf(gx);

            // quad-entry coords: ri = y0+1 (row OOB -> SRD returns 0),
            // ke = clamp(x0+1) with zero weights on clamped x.
            const int ri = y0i + 1;
            const int ke = min(max(x0i + 1, 0), ENT - 1);
            const unsigned off = (unsigned)ri * (unsigned)ROW_BYTES + ((unsigned)ke << 3);

            // exec-masked load: lanes whose cell is unchanged produce no
            // memory transaction (TA lines scale with active lanes).
            if (off != prevOff) {
                pf = llvm_amdgcn_raw_buffer_load_2fp32(rsrc, (int)off, 0, 0);
            }
            prevOff = off;

            union { floatx2 f; half4v h; } cv;
            cv.f = pf;
            const float v00 = (float)cv.h.x;
            const float v01 = (float)cv.h.y;
            const float v10 = (float)cv.h.z;
            const float v11 = (float)cv.h.w;

            const bool vx0 = (unsigned)x0i < (unsigned)WID;
            const bool vx1 = (unsigned)(x0i + 1) < (unsigned)WID;
            const float zx0 = vx0 ? (1.0f - wxf) : 0.0f;
            const float zx1 = vx1 ? wxf : 0.0f;

            const float row0 = fmaf(v01, zx1, v00 * zx0);
            const float row1 = fmaf(v11, zx1, v10 * zx0);

            if (s & 1) {
                acc1 = fmaf(1.0f - wyf, row0, acc1);
                acc1 = fmaf(wyf,        row1, acc1);
            } else {
                acc0 = fmaf(1.0f - wyf, row0, acc0);
                acc0 = fmaf(wyf,        row1, acc0);
            }
        }
    }

    out[idx] = (acc0 + acc1) / (float)(K_SIZE * K_SIZE);
}

// ---------------- fallback: direct fp32 gather (proven, ~55us) ----------------
__global__ __launch_bounds__(256) void fused_sample_kernel_f32(
    const float* __restrict__ input,
    const float* __restrict__ Lp,
    const float* __restrict__ wbuf,
    float* __restrict__ out)
{
#pragma clang fp contract(off)
    const int idx = blockIdx.x * blockDim.x + threadIdx.x;
    const int b = blockIdx.x >> 10;
    const int p = idx & (HW - 1);
    const int y = p >> 9;
    const int x = p & (WID - 1);

    union {
        struct { const void* base; unsigned num; unsigned cfg; } s;
        int32x4 v;
    } desc;
    desc.s.base = (const void*)(input + (size_t)b * HW);
    desc.s.num  = HW * 4u;
    desc.s.cfg  = 0x00020000u;
    const int32x4 rsrc = desc.v;

    const size_t l_off = (size_t)idx * 3;
    const float L0 = Lp[l_off + 0];
    const float L1 = Lp[l_off + 1];
    const float L2 = Lp[l_off + 2];

    const float a  = fabsf(L0) + EPS_L;
    const float bb = L1;
    const float c  = fabsf(L2) + EPS_L;

    const float M00 = a * a;
    const float M01 = a * bb;
    const float M11 = (bb * bb) + (c * c);

    const float d00 = M00 + EPS;
    const float d11 = M11 + EPS;
    const float det = (d00 * d11) - (M01 * M01);
    const float I00 = d11 / det;
    const float I01 = (-M01) / det;
    const float I11 = d00 / det;

    const float wx = wbuf[(size_t)b * 2 * HW + p];
    const float wy = wbuf[(size_t)b * 2 * HW + HW + p];

    const float q    = (((I00 * wx) * wx) + (((2.0f * I01) * wx) * wy)) + ((I11 * wy) * wy);
    const float norm = sqrtf(q + EPS);
    const float e    = (float)exp((double)(-norm));
    const float sig  = 1.0f / (1.0f + e);
    const float tuned = ((sig - 0.5f) * 2.0f) * (1.0f - EPS_W);
    const float scale = tuned / (norm + EPS);
    const float wtx = wx * scale;
    const float wty = wy * scale;

    const float CT[K_SIZE] = { 1.0f,  0.30901696090f, -0.80901703575f, -0.80901693229f,  0.30901712828f };
    const float ST[K_SIZE] = { 0.0f,  0.95105652717f,  0.58778519534f, -0.58778533774f, -0.95105647279f };
    const float SV[K_SIZE] = { 0.2f, 0.4f, 0.6f, 0.8f, 1.0f };

    const float fy = (float)y;
    const float fx = (float)x;

    float acc0 = 0.0f;
    float acc1 = 0.0f;

    #pragma unroll
    for (int k = 0; k < K_SIZE; ++k) {
        const float ct = CT[k];
        const float st = ST[k];
        const float quad = (((M00 * ct) * ct) + (((2.0f * M01) * ct) * st)) + ((M11 * st) * st);
        const float F    = (sqrtf(quad) + (wtx * ct)) + (wty * st);
        const float Fe   = F + EPS;
        const float rFe  = __builtin_amdgcn_rcpf(Fe);
        const float yx   = ct * rFe;
        const float yy   = st * rFe;

        #pragma unroll
        for (int s = 0; s < K_SIZE; ++s) {
            const float sv = SV[s];
            const float gy = fmaf(sv, yy, fy);
            const float gx = fmaf(sv, yx, fx);

            const int   y0i = (int)floorf(gy);
            const int   x0i = (int)floorf(gx);
            const float wyf = __builtin_amdgcn_fractf(gy);
            const float wxf = __builtin_amdgcn_fractf(gx);

            const unsigned r0 = (unsigned)y0i << 11;
            const unsigned r1 = r0 + (WID * 4u);

            const int x1i = x0i + 1;
            const bool vx0 = (unsigned)x0i < (unsigned)WID;
            const bool vx1 = (unsigned)x1i < (unsigned)WID;
            const unsigned x0v = (unsigned)min(max(x0i, 0), WID - 1) << 2;
            const unsigned x1v = (unsigned)min(max(x1i, 0), WID - 1) << 2;

            const float v00 = llvm_amdgcn_raw_buffer_load_fp32(rsrc, (int)(r0 + x0v), 0, 0);
            const float v01 = llvm_amdgcn_raw_buffer_load_fp32(rsrc, (int)(r0 + x1v), 0, 0);
            const float v10 = llvm_amdgcn_raw_buffer_load_fp32(rsrc, (int)(r1 + x0v), 0, 0);
            const float v11 = llvm_amdgcn_raw_buffer_load_fp32(rsrc, (int)(r1 + x1v), 0, 0);

            const float zx0 = vx0 ? (1.0f - wxf) : 0.0f;
            const float zx1 = vx1 ? wxf : 0.0f;

            const float row0 = fmaf(v01, zx1, v00 * zx0);
            const float row1 = fmaf(v11, zx1, v10 * zx0);

            if (s & 1) {
                acc1 = fmaf(1.0f - wyf, row0, acc1);
                acc1 = fmaf(wyf,        row1, acc1);
            } else {
                acc0 = fmaf(1.0f - wyf, row0, acc0);
                acc0 = fmaf(wyf,        row1, acc0);
            }
        }
    }

    out[idx] = (acc0 + acc1) / (float)(K_SIZE * K_SIZE);
}

extern "C" void kernel_launch(void* const* d_in, const int* in_sizes, int n_in,
                              void* d_out, int out_size, void* d_ws, size_t ws_size,
                              hipStream_t stream) {
    const float* input = (const float*)d_in[0];
    const float* Lp    = (const float*)d_in[1];
    const float* wbuf  = (const float*)d_in[2];
    float* out = (float*)d_out;

    if (ws_size >= TBL_BYTES) {
        char* tbl = (char*)d_ws;
        const int pack_total = BATCH * ENT * ENT;              // 1,052,676
        pack_kernel<<<(pack_total + 255) / 256, 256, 0, stream>>>(input, tbl);
        fused_sample_kernel_f16<<<BATCH * HW / 256, 256, 0, stream>>>(tbl, Lp, wbuf, out);
    } else {
        fused_sample_kernel_f32<<<BATCH * HW / 256, 256, 0, stream>>>(input, Lp, wbuf, out);
    }
}

// Round 10
// 64.391 us; speedup vs baseline: 1.3595x; 1.3595x over previous
//
#include <hip/hip_runtime.h>
#include <math.h>

#define K_SIZE 5
#define EPS    1e-6f
#define EPS_L  1e-3f
#define EPS_W  1e-3f

#define BATCH 4
#define HGT   512
#define WID   512
#define HW    (HGT * WID)

// fp16 quad table: entry[b][ri][k] (ri,k in 0..512) =
//   { img[ri-1][k-1], img[ri-1][k], img[ri][k-1], img[ri][k] }  (OOB halves = 0)
// ri = y0+1, k = x0+1. One 8B load -> all 4 bilinear corners.
#define ENT        513
#define ROW_ENTRIES 520                         // pad for 64B-aligned rows
#define ROW_BYTES  (ROW_ENTRIES * 8)            // 4160 = 64*65
#define IMG_BYTES  (ENT * ROW_BYTES)            // 2,134,080
#define TBL_BYTES  ((size_t)BATCH * IMG_BYTES)  // ~8.5 MB

// LDS window: rows ri in [y-5, y+6] (12), entries k in [xs-5, xs+262] (268)
#define WROWS 12
#define WCOLS 268
#define WR_OFF 5            // rbase = y + 1 - 6 = y - 5
#define WC_OFF 5            // kbase = xs + 1 - 6 = xs - 5

typedef int int32x4 __attribute__((ext_vector_type(4)));
typedef float floatx2 __attribute__((ext_vector_type(2)));
typedef _Float16 half4v __attribute__((ext_vector_type(4)));

// Raw buffer loads with hardware bounds check: OOB -> returns 0
__device__ float llvm_amdgcn_raw_buffer_load_fp32(int32x4 srsrc, int voffset,
                                                  int soffset, int aux)
    __asm("llvm.amdgcn.raw.buffer.load.f32");
__device__ floatx2 llvm_amdgcn_raw_buffer_load_2fp32(int32x4 srsrc, int voffset,
                                                     int soffset, int aux)
    __asm("llvm.amdgcn.raw.buffer.load.v2f32");

// ---------------- pack: f32 image -> fp16 quad table ----------------
__global__ __launch_bounds__(256) void pack_kernel(
    const float* __restrict__ input, char* __restrict__ tbl)
{
    const int t = blockIdx.x * blockDim.x + threadIdx.x;
    if (t >= BATCH * ENT * ENT) return;
    const int k  = t % ENT;
    const int ri = (t / ENT) % ENT;
    const int b  = t / (ENT * ENT);

    const float* __restrict__ img = input + (size_t)b * HW;

    const bool top = (ri >= 1), bot = (ri <= HGT - 1);
    const bool lef = (k  >= 1), rig = (k  <= WID - 1);
    const int yT = (ri - 1) << 9;
    const int yB = ri << 9;

    union { half4v h; floatx2 f; } cv;
    cv.h.x = (_Float16)((top && lef) ? img[yT + k - 1] : 0.0f);
    cv.h.y = (_Float16)((top && rig) ? img[yT + k]     : 0.0f);
    cv.h.z = (_Float16)((bot && lef) ? img[yB + k - 1] : 0.0f);
    cv.h.w = (_Float16)((bot && rig) ? img[yB + k]     : 0.0f);

    floatx2* dst = (floatx2*)(tbl + (size_t)b * IMG_BYTES + (size_t)ri * ROW_BYTES + ((size_t)k << 3));
    *dst = cv.f;
}

// ------- main fused kernel: LDS window cache + rare global fallback -------
__global__ __launch_bounds__(256) void fused_sample_kernel_f16(
    const char* __restrict__ tbl,      // packed table in ws
    const float* __restrict__ Lp,      // (B,H,W,3)
    const float* __restrict__ wbuf,    // (B,2,H,W)
    float* __restrict__ out)           // (B,1,H,W)
{
#pragma clang fp contract(off)
    __shared__ floatx2 tile[WROWS * WCOLS];     // 25,728 B

    const int idx = blockIdx.x * blockDim.x + threadIdx.x;

    const int b = blockIdx.x >> 10;     // 1024 blocks per image (uniform per block)
    const int p = idx & (HW - 1);
    const int y = p >> 9;
    const int x = p & (WID - 1);

    // block covers x in [xs, xs+255] of row y (wave-uniform)
    const int xs    = (blockIdx.x & 1) << 8;
    const int rbase = y - WR_OFF;               // staged rows: ri in [rbase, rbase+11]
    const int kbase = xs - WC_OFF;              // staged cols: k  in [kbase, kbase+267]

    // SRD over this image's table: OOB -> 0.
    union {
        struct { const void* base; unsigned num; unsigned cfg; } s;
        int32x4 v;
    } desc;
    desc.s.base = (const void*)(tbl + (size_t)b * IMG_BYTES);
    desc.s.num  = (unsigned)IMG_BYTES;
    desc.s.cfg  = 0x00020000u;
    const int32x4 rsrc = desc.v;

    // ---- stage the window (coalesced; OOB rows/cols arrive as 0/junk;
    //      junk cols (k>512) are never consumed since ke<=512) ----
    for (int i = threadIdx.x; i < WROWS * WCOLS; i += 256) {
        const int rr = i / WCOLS;
        const int kk = i - rr * WCOLS;
        const int ri = rbase + rr;
        const int k  = kbase + kk;
        const unsigned off = (unsigned)(ri * ROW_BYTES + (k << 3));
        tile[i] = llvm_amdgcn_raw_buffer_load_2fp32(rsrc, (int)off, 0, 0);
    }

    // ---- per-pixel matrix (exactly mirrors numpy op order; amplified path) ----
    const size_t l_off = (size_t)idx * 3;
    const float L0 = Lp[l_off + 0];
    const float L1 = Lp[l_off + 1];
    const float L2 = Lp[l_off + 2];

    const float a  = fabsf(L0) + EPS_L;
    const float bb = L1;
    const float c  = fabsf(L2) + EPS_L;

    const float M00 = a * a;
    const float M01 = a * bb;
    const float M11 = (bb * bb) + (c * c);

    const float d00 = M00 + EPS;
    const float d11 = M11 + EPS;
    const float det = (d00 * d11) - (M01 * M01);
    const float I00 = d11 / det;          // IEEE f32 div, same as np
    const float I01 = (-M01) / det;
    const float I11 = d00 / det;

    const float wx = wbuf[(size_t)b * 2 * HW + p];
    const float wy = wbuf[(size_t)b * 2 * HW + HW + p];

    const float q    = (((I00 * wx) * wx) + (((2.0f * I01) * wx) * wy)) + ((I11 * wy) * wy);
    const float norm = sqrtf(q + EPS);

    const float e    = (float)exp((double)(-norm));   // correctly-rounded f32 exp
    const float sig  = 1.0f / (1.0f + e);
    const float tuned = ((sig - 0.5f) * 2.0f) * (1.0f - EPS_W);
    const float scale = tuned / (norm + EPS);         // IEEE div
    const float wtx = wx * scale;
    const float wty = wy * scale;

    // cos/sin of the FLOAT32-ROUNDED theta_k
    const float CT[K_SIZE] = { 1.0f,  0.30901696090f, -0.80901703575f, -0.80901693229f,  0.30901712828f };
    const float ST[K_SIZE] = { 0.0f,  0.95105652717f,  0.58778519534f, -0.58778533774f, -0.95105647279f };
    const float SV[K_SIZE] = { 0.2f, 0.4f, 0.6f, 0.8f, 1.0f };

    const float fy = (float)y;
    const float fx = (float)x;

    float acc0 = 0.0f;
    float acc1 = 0.0f;

    __syncthreads();

    #pragma unroll
    for (int k = 0; k < K_SIZE; ++k) {
        const float ct = CT[k];
        const float st = ST[k];
        // amplified path: keep exact left-assoc, no contraction
        const float quad = (((M00 * ct) * ct) + (((2.0f * M01) * ct) * st)) + ((M11 * st) * st);
        const float F    = (sqrtf(quad) + (wtx * ct)) + (wty * st);
        const float Fe   = F + EPS;
        // downstream of cancellation: approx rcp safe (position error ~1e-7 rel)
        const float rFe  = __builtin_amdgcn_rcpf(Fe);
        const float yx   = ct * rFe;
        const float yy   = st * rFe;

        #pragma unroll
        for (int s = 0; s < K_SIZE; ++s) {
            const float sv = SV[s];
            const float gy = fmaf(sv, yy, fy);
            const float gx = fmaf(sv, yx, fx);

            const int   y0i = (int)floorf(gy);      // v_cvt_flr_i32_f32
            const int   x0i = (int)floorf(gx);
            const float wyf = __builtin_amdgcn_fractf(gy);
            const float wxf = __builtin_amdgcn_fractf(gx);

            // quad-entry coords: ri = y0+1, ke = clamp(x0+1, 0, 512)
            const int ri = y0i + 1;
            const int ke = min(max(x0i + 1, 0), ENT - 1);

            // window test + clamped LDS index (no carried state, no chains)
            const int iri = ri - rbase;
            const int ike = ke - kbase;
            const bool inWin = ((unsigned)iri < (unsigned)WROWS) &
                               ((unsigned)ike < (unsigned)WCOLS);
            const int lidx = min(max(iri, 0), WROWS - 1) * WCOLS
                           + min(max(ike, 0), WCOLS - 1);

            floatx2 qv = tile[lidx];                // unconditional ds_read_b64
            if (!inWin) {                           // rare: exec-masked global
                const unsigned off = (unsigned)ri * (unsigned)ROW_BYTES
                                   + ((unsigned)ke << 3);
                qv = llvm_amdgcn_raw_buffer_load_2fp32(rsrc, (int)off, 0, 0);
            }

            union { floatx2 f; half4v h; } cv;
            cv.f = qv;
            const float v00 = (float)cv.h.x;
            const float v01 = (float)cv.h.y;
            const float v10 = (float)cv.h.z;
            const float v11 = (float)cv.h.w;

            const bool vx0 = (unsigned)x0i < (unsigned)WID;
            const bool vx1 = (unsigned)(x0i + 1) < (unsigned)WID;
            const float zx0 = vx0 ? (1.0f - wxf) : 0.0f;
            const float zx1 = vx1 ? wxf : 0.0f;

            const float row0 = fmaf(v01, zx1, v00 * zx0);
            const float row1 = fmaf(v11, zx1, v10 * zx0);

            if (s & 1) {
                acc1 = fmaf(1.0f - wyf, row0, acc1);
                acc1 = fmaf(wyf,        row1, acc1);
            } else {
                acc0 = fmaf(1.0f - wyf, row0, acc0);
                acc0 = fmaf(wyf,        row1, acc0);
            }
        }
    }

    out[idx] = (acc0 + acc1) / (float)(K_SIZE * K_SIZE);
}

// ---------------- fallback: direct fp32 gather (proven, ~55us) ----------------
__global__ __launch_bounds__(256) void fused_sample_kernel_f32(
    const float* __restrict__ input,
    const float* __restrict__ Lp,
    const float* __restrict__ wbuf,
    float* __restrict__ out)
{
#pragma clang fp contract(off)
    const int idx = blockIdx.x * blockDim.x + threadIdx.x;
    const int b = blockIdx.x >> 10;
    const int p = idx & (HW - 1);
    const int y = p >> 9;
    const int x = p & (WID - 1);

    union {
        struct { const void* base; unsigned num; unsigned cfg; } s;
        int32x4 v;
    } desc;
    desc.s.base = (const void*)(input + (size_t)b * HW);
    desc.s.num  = HW * 4u;
    desc.s.cfg  = 0x00020000u;
    const int32x4 rsrc = desc.v;

    const size_t l_off = (size_t)idx * 3;
    const float L0 = Lp[l_off + 0];
    const float L1 = Lp[l_off + 1];
    const float L2 = Lp[l_off + 2];

    const float a  = fabsf(L0) + EPS_L;
    const float bb = L1;
    const float c  = fabsf(L2) + EPS_L;

    const float M00 = a * a;
    const float M01 = a * bb;
    const float M11 = (bb * bb) + (c * c);

    const float d00 = M00 + EPS;
    const float d11 = M11 + EPS;
    const float det = (d00 * d11) - (M01 * M01);
    const float I00 = d11 / det;
    const float I01 = (-M01) / det;
    const float I11 = d00 / det;

    const float wx = wbuf[(size_t)b * 2 * HW + p];
    const float wy = wbuf[(size_t)b * 2 * HW + HW + p];

    const float q    = (((I00 * wx) * wx) + (((2.0f * I01) * wx) * wy)) + ((I11 * wy) * wy);
    const float norm = sqrtf(q + EPS);
    const float e    = (float)exp((double)(-norm));
    const float sig  = 1.0f / (1.0f + e);
    const float tuned = ((sig - 0.5f) * 2.0f) * (1.0f - EPS_W);
    const float scale = tuned / (norm + EPS);
    const float wtx = wx * scale;
    const float wty = wy * scale;

    const float CT[K_SIZE] = { 1.0f,  0.30901696090f, -0.80901703575f, -0.80901693229f,  0.30901712828f };
    const float ST[K_SIZE] = { 0.0f,  0.95105652717f,  0.58778519534f, -0.58778533774f, -0.95105647279f };
    const float SV[K_SIZE] = { 0.2f, 0.4f, 0.6f, 0.8f, 1.0f };

    const float fy = (float)y;
    const float fx = (float)x;

    float acc0 = 0.0f;
    float acc1 = 0.0f;

    #pragma unroll
    for (int k = 0; k < K_SIZE; ++k) {
        const float ct = CT[k];
        const float st = ST[k];
        const float quad = (((M00 * ct) * ct) + (((2.0f * M01) * ct) * st)) + ((M11 * st) * st);
        const float F    = (sqrtf(quad) + (wtx * ct)) + (wty * st);
        const float Fe   = F + EPS;
        const float rFe  = __builtin_amdgcn_rcpf(Fe);
        const float yx   = ct * rFe;
        const float yy   = st * rFe;

        #pragma unroll
        for (int s = 0; s < K_SIZE; ++s) {
            const float sv = SV[s];
            const float gy = fmaf(sv, yy, fy);
            const float gx = fmaf(sv, yx, fx);

            const int   y0i = (int)floorf(gy);
            const int   x0i = (int)floorf(gx);
            const float wyf = __builtin_amdgcn_fractf(gy);
            const float wxf = __builtin_amdgcn_fractf(gx);

            const unsigned r0 = (unsigned)y0i << 11;
            const unsigned r1 = r0 + (WID * 4u);

            const int x1i = x0i + 1;
            const bool vx0 = (unsigned)x0i < (unsigned)WID;
            const bool vx1 = (unsigned)x1i < (unsigned)WID;
            const unsigned x0v = (unsigned)min(max(x0i, 0), WID - 1) << 2;
            const unsigned x1v = (unsigned)min(max(x1i, 0), WID - 1) << 2;

            const float v00 = llvm_amdgcn_raw_buffer_load_fp32(rsrc, (int)(r0 + x0v), 0, 0);
            const float v01 = llvm_amdgcn_raw_buffer_load_fp32(rsrc, (int)(r0 + x1v), 0, 0);
            const float v10 = llvm_amdgcn_raw_buffer_load_fp32(rsrc, (int)(r1 + x0v), 0, 0);
            const float v11 = llvm_amdgcn_raw_buffer_load_fp32(rsrc, (int)(r1 + x1v), 0, 0);

            const float zx0 = vx0 ? (1.0f - wxf) : 0.0f;
            const float zx1 = vx1 ? wxf : 0.0f;

            const float row0 = fmaf(v01, zx1, v00 * zx0);
            const float row1 = fmaf(v11, zx1, v10 * zx0);

            if (s & 1) {
                acc1 = fmaf(1.0f - wyf, row0, acc1);
                acc1 = fmaf(wyf,        row1, acc1);
            } else {
                acc0 = fmaf(1.0f - wyf, row0, acc0);
                acc0 = fmaf(wyf,        row1, acc0);
            }
        }
    }

    out[idx] = (acc0 + acc1) / (float)(K_SIZE * K_SIZE);
}

extern "C" void kernel_launch(void* const* d_in, const int* in_sizes, int n_in,
                              void* d_out, int out_size, void* d_ws, size_t ws_size,
                              hipStream_t stream) {
    const float* input = (const float*)d_in[0];
    const float* Lp    = (const float*)d_in[1];
    const float* wbuf  = (const float*)d_in[2];
    float* out = (float*)d_out;

    if (ws_size >= TBL_BYTES) {
        char* tbl = (char*)d_ws;
        const int pack_total = BATCH * ENT * ENT;              // 1,052,676
        pack_kernel<<<(pack_total + 255) / 256, 256, 0, stream>>>(input, tbl);
        fused_sample_kernel_f16<<<BATCH * HW / 256, 256, 0, stream>>>(tbl, Lp, wbuf, out);
    } else {
        fused_sample_kernel_f32<<<BATCH * HW / 256, 256, 0, stream>>>(input, Lp, wbuf, out);
    }
}

// Round 12
// 41.101 us; speedup vs baseline: 2.1299x; 1.5667x over previous
//
#include <hip/hip_runtime.h>
#include <math.h>

#define K_SIZE 5
#define EPS    1e-6f
#define EPS_L  1e-3f
#define EPS_W  1e-3f

#define BATCH 4
#define HGT   512
#define WID   512
#define HW    (HGT * WID)

// fp16 quad table: entry[b][ri][k] (ri,k in 0..512) =
//   { img[ri-1][k-1], img[ri-1][k], img[ri][k-1], img[ri][k] }  (OOB halves = 0)
// ri = y0+1, k = x0+1. One 8B load -> all 4 bilinear corners.
#define ENT        513
#define ROW_ENTRIES 520                         // pad for 64B-aligned rows
#define ROW_BYTES  (ROW_ENTRIES * 8)            // 4160 = 64*65
#define IMG_BYTES  (ENT * ROW_BYTES)            // 2,134,080
#define TBL_BYTES  ((size_t)BATCH * IMG_BYTES)  // ~8.5 MB

#define NS (K_SIZE * K_SIZE)                    // 25 samples

typedef int int32x4 __attribute__((ext_vector_type(4)));
typedef float floatx2 __attribute__((ext_vector_type(2)));
typedef _Float16 half4v __attribute__((ext_vector_type(4)));

// Raw buffer loads with hardware bounds check: OOB -> returns 0
__device__ float llvm_amdgcn_raw_buffer_load_fp32(int32x4 srsrc, int voffset,
                                                  int soffset, int aux)
    __asm("llvm.amdgcn.raw.buffer.load.f32");
__device__ floatx2 llvm_amdgcn_raw_buffer_load_2fp32(int32x4 srsrc, int voffset,
                                                     int soffset, int aux)
    __asm("llvm.amdgcn.raw.buffer.load.v2f32");

// ---------------- pack: f32 image -> fp16 quad table ----------------
__global__ __launch_bounds__(256) void pack_kernel(
    const float* __restrict__ input, char* __restrict__ tbl)
{
    const int t = blockIdx.x * blockDim.x + threadIdx.x;
    if (t >= BATCH * ENT * ENT) return;
    const int k  = t % ENT;
    const int ri = (t / ENT) % ENT;
    const int b  = t / (ENT * ENT);

    const float* __restrict__ img = input + (size_t)b * HW;

    const bool top = (ri >= 1), bot = (ri <= HGT - 1);
    const bool lef = (k  >= 1), rig = (k  <= WID - 1);
    const int yT = (ri - 1) << 9;
    const int yB = ri << 9;

    union { half4v h; floatx2 f; } cv;
    cv.h.x = (_Float16)((top && lef) ? img[yT + k - 1] : 0.0f);
    cv.h.y = (_Float16)((top && rig) ? img[yT + k]     : 0.0f);
    cv.h.z = (_Float16)((bot && lef) ? img[yB + k - 1] : 0.0f);
    cv.h.w = (_Float16)((bot && rig) ? img[yB + k]     : 0.0f);

    floatx2* dst = (floatx2*)(tbl + (size_t)b * IMG_BYTES + (size_t)ri * ROW_BYTES + ((size_t)k << 3));
    *dst = cv.f;
}

// --- main fused kernel: phase-split gather, compiler-managed waits ---
__global__ __launch_bounds__(256) void fused_sample_kernel_f16(
    const char* __restrict__ tbl,      // packed table in ws
    const float* __restrict__ Lp,      // (B,H,W,3)
    const float* __restrict__ wbuf,    // (B,2,H,W)
    float* __restrict__ out)           // (B,1,H,W)
{
#pragma clang fp contract(off)
    const int idx = blockIdx.x * blockDim.x + threadIdx.x;

    const int b = blockIdx.x >> 10;     // 1024 blocks per image (uniform per block)
    const int p = idx & (HW - 1);
    const int y = p >> 9;
    const int x = p & (WID - 1);

    // SRD over this image's table: OOB -> 0.
    union {
        struct { const void* base; unsigned num; unsigned cfg; } s;
        int32x4 v;
    } desc;
    desc.s.base = (const void*)(tbl + (size_t)b * IMG_BYTES);
    desc.s.num  = (unsigned)IMG_BYTES;
    desc.s.cfg  = 0x00020000u;
    const int32x4 rsrc = desc.v;

    // ---- per-pixel matrix (exactly mirrors numpy op order; amplified path) ----
    const size_t l_off = (size_t)idx * 3;
    const float L0 = Lp[l_off + 0];
    const float L1 = Lp[l_off + 1];
    const float L2 = Lp[l_off + 2];

    const float a  = fabsf(L0) + EPS_L;
    const float bb = L1;
    const float c  = fabsf(L2) + EPS_L;

    const float M00 = a * a;
    const float M01 = a * bb;
    const float M11 = (bb * bb) + (c * c);

    const float d00 = M00 + EPS;
    const float d11 = M11 + EPS;
    const float det = (d00 * d11) - (M01 * M01);
    const float I00 = d11 / det;          // IEEE f32 div, same as np
    const float I01 = (-M01) / det;
    const float I11 = d00 / det;

    const float wx = wbuf[(size_t)b * 2 * HW + p];
    const float wy = wbuf[(size_t)b * 2 * HW + HW + p];

    const float q    = (((I00 * wx) * wx) + (((2.0f * I01) * wx) * wy)) + ((I11 * wy) * wy);
    const float norm = sqrtf(q + EPS);

    const float e    = (float)exp((double)(-norm));   // correctly-rounded f32 exp
    const float sig  = 1.0f / (1.0f + e);
    const float tuned = ((sig - 0.5f) * 2.0f) * (1.0f - EPS_W);
    const float scale = tuned / (norm + EPS);         // IEEE div
    const float wtx = wx * scale;
    const float wty = wy * scale;

    // cos/sin of the FLOAT32-ROUNDED theta_k
    const float CT[K_SIZE] = { 1.0f,  0.30901696090f, -0.80901703575f, -0.80901693229f,  0.30901712828f };
    const float ST[K_SIZE] = { 0.0f,  0.95105652717f,  0.58778519534f, -0.58778533774f, -0.95105647279f };
    const float SV[K_SIZE] = { 0.2f, 0.4f, 0.6f, 0.8f, 1.0f };

    const float fy = (float)y;
    const float fx = (float)x;

    // ---- ray directions (per k), kept live through consume ----
    float vxA[K_SIZE], vyA[K_SIZE];
    #pragma unroll
    for (int k = 0; k < K_SIZE; ++k) {
        const float ct = CT[k];
        const float st = ST[k];
        // amplified path: keep exact left-assoc, no contraction
        const float quad = (((M00 * ct) * ct) + (((2.0f * M01) * ct) * st)) + ((M11 * st) * st);
        const float F    = (sqrtf(quad) + (wtx * ct)) + (wty * st);
        const float Fe   = F + EPS;
        // downstream of cancellation: approx rcp safe (position error ~1e-7 rel)
        const float rFe  = __builtin_amdgcn_rcpf(Fe);
        vxA[k] = ct * rFe;
        vyA[k] = st * rFe;
    }

    // ---- phase 1: issue all 25 quad loads (intrinsic -> compiler-tracked).
    //      sched_barrier(0) pins them above the consume phase so they
    //      stay in flight together (the scheduler sank them in R6). ----
    floatx2 dstA[NS];
    #pragma unroll
    for (int i = 0; i < NS; ++i) {
        const int k = i / K_SIZE;
        const int s = i - k * K_SIZE;
        const float gy = fmaf(SV[s], vyA[k], fy);
        const float gx = fmaf(SV[s], vxA[k], fx);
        const int y0i = (int)floorf(gy);
        const int x0i = (int)floorf(gx);
        const int ri = y0i + 1;
        const int ke = min(max(x0i + 1, 0), ENT - 1);
        const unsigned off = (unsigned)ri * (unsigned)ROW_BYTES + ((unsigned)ke << 3);
        dstA[i] = llvm_amdgcn_raw_buffer_load_2fp32(rsrc, (int)off, 0, 0);
    }

    __builtin_amdgcn_sched_barrier(0);

    float acc0 = 0.0f;
    float acc1 = 0.0f;

    // ---- phase 2: consume (weights recomputed -> bit-identical to R8) ----
    #pragma unroll
    for (int i = 0; i < NS; ++i) {
        const int k = i / K_SIZE;
        const int s = i - k * K_SIZE;
        const float gy = fmaf(SV[s], vyA[k], fy);
        const float gx = fmaf(SV[s], vxA[k], fx);
        const int   x0i = (int)floorf(gx);
        const float wyf = __builtin_amdgcn_fractf(gy);
        const float wxf = __builtin_amdgcn_fractf(gx);

        union { floatx2 f; half4v h; } cv;
        cv.f = dstA[i];
        const float v00 = (float)cv.h.x;
        const float v01 = (float)cv.h.y;
        const float v10 = (float)cv.h.z;
        const float v11 = (float)cv.h.w;

        const bool vx0 = (unsigned)x0i < (unsigned)WID;
        const bool vx1 = (unsigned)(x0i + 1) < (unsigned)WID;
        const float zx0 = vx0 ? (1.0f - wxf) : 0.0f;
        const float zx1 = vx1 ? wxf : 0.0f;

        const float row0 = fmaf(v01, zx1, v00 * zx0);
        const float row1 = fmaf(v11, zx1, v10 * zx0);

        if (s & 1) {
            acc1 = fmaf(1.0f - wyf, row0, acc1);
            acc1 = fmaf(wyf,        row1, acc1);
        } else {
            acc0 = fmaf(1.0f - wyf, row0, acc0);
            acc0 = fmaf(wyf,        row1, acc0);
        }
    }

    out[idx] = (acc0 + acc1) / (float)(K_SIZE * K_SIZE);
}

// ---------------- fallback: direct fp32 gather (proven, ~55us) ----------------
__global__ __launch_bounds__(256) void fused_sample_kernel_f32(
    const float* __restrict__ input,
    const float* __restrict__ Lp,
    const float* __restrict__ wbuf,
    float* __restrict__ out)
{
#pragma clang fp contract(off)
    const int idx = blockIdx.x * blockDim.x + threadIdx.x;
    const int b = blockIdx.x >> 10;
    const int p = idx & (HW - 1);
    const int y = p >> 9;
    const int x = p & (WID - 1);

    union {
        struct { const void* base; unsigned num; unsigned cfg; } s;
        int32x4 v;
    } desc;
    desc.s.base = (const void*)(input + (size_t)b * HW);
    desc.s.num  = HW * 4u;
    desc.s.cfg  = 0x00020000u;
    const int32x4 rsrc = desc.v;

    const size_t l_off = (size_t)idx * 3;
    const float L0 = Lp[l_off + 0];
    const float L1 = Lp[l_off + 1];
    const float L2 = Lp[l_off + 2];

    const float a  = fabsf(L0) + EPS_L;
    const float bb = L1;
    const float c  = fabsf(L2) + EPS_L;

    const float M00 = a * a;
    const float M01 = a * bb;
    const float M11 = (bb * bb) + (c * c);

    const float d00 = M00 + EPS;
    const float d11 = M11 + EPS;
    const float det = (d00 * d11) - (M01 * M01);
    const float I00 = d11 / det;
    const float I01 = (-M01) / det;
    const float I11 = d00 / det;

    const float wx = wbuf[(size_t)b * 2 * HW + p];
    const float wy = wbuf[(size_t)b * 2 * HW + HW + p];

    const float q    = (((I00 * wx) * wx) + (((2.0f * I01) * wx) * wy)) + ((I11 * wy) * wy);
    const float norm = sqrtf(q + EPS);
    const float e    = (float)exp((double)(-norm));
    const float sig  = 1.0f / (1.0f + e);
    const float tuned = ((sig - 0.5f) * 2.0f) * (1.0f - EPS_W);
    const float scale = tuned / (norm + EPS);
    const float wtx = wx * scale;
    const float wty = wy * scale;

    const float CT[K_SIZE] = { 1.0f,  0.30901696090f, -0.80901703575f, -0.80901693229f,  0.30901712828f };
    const float ST[K_SIZE] = { 0.0f,  0.95105652717f,  0.58778519534f, -0.58778533774f, -0.95105647279f };
    const float SV[K_SIZE] = { 0.2f, 0.4f, 0.6f, 0.8f, 1.0f };

    const float fy = (float)y;
    const float fx = (float)x;

    float acc0 = 0.0f;
    float acc1 = 0.0f;

    #pragma unroll
    for (int k = 0; k < K_SIZE; ++k) {
        const float ct = CT[k];
        const float st = ST[k];
        const float quad = (((M00 * ct) * ct) + (((2.0f * M01) * ct) * st)) + ((M11 * st) * st);
        const float F    = (sqrtf(quad) + (wtx * ct)) + (wty * st);
        const float Fe   = F + EPS;
        const float rFe  = __builtin_amdgcn_rcpf(Fe);
        const float yx   = ct * rFe;
        const float yy   = st * rFe;

        #pragma unroll
        for (int s = 0; s < K_SIZE; ++s) {
            const float sv = SV[s];
            const float gy = fmaf(sv, yy, fy);
            const float gx = fmaf(sv, yx, fx);

            const int   y0i = (int)floorf(gy);
            const int   x0i = (int)floorf(gx);
            const float wyf = __builtin_amdgcn_fractf(gy);
            const float wxf = __builtin_amdgcn_fractf(gx);

            const unsigned r0 = (unsigned)y0i << 11;
            const unsigned r1 = r0 + (WID * 4u);

            const int x1i = x0i + 1;
            const bool vx0 = (unsigned)x0i < (unsigned)WID;
            const bool vx1 = (unsigned)x1i < (unsigned)WID;
            const unsigned x0v = (unsigned)min(max(x0i, 0), WID - 1) << 2;
            const unsigned x1v = (unsigned)min(max(x1i, 0), WID - 1) << 2;

            const float v00 = llvm_amdgcn_raw_buffer_load_fp32(rsrc, (int)(r0 + x0v), 0, 0);
            const float v01 = llvm_amdgcn_raw_buffer_load_fp32(rsrc, (int)(r0 + x1v), 0, 0);
            const float v10 = llvm_amdgcn_raw_buffer_load_fp32(rsrc, (int)(r1 + x0v), 0, 0);
            const float v11 = llvm_amdgcn_raw_buffer_load_fp32(rsrc, (int)(r1 + x1v), 0, 0);

            const float zx0 = vx0 ? (1.0f - wxf) : 0.0f;
            const float zx1 = vx1 ? wxf : 0.0f;

            const float row0 = fmaf(v01, zx1, v00 * zx0);
            const float row1 = fmaf(v11, zx1, v10 * zx0);

            if (s & 1) {
                acc1 = fmaf(1.0f - wyf, row0, acc1);
                acc1 = fmaf(wyf,        row1, acc1);
            } else {
                acc0 = fmaf(1.0f - wyf, row0, acc0);
                acc0 = fmaf(wyf,        row1, acc0);
            }
        }
    }

    out[idx] = (acc0 + acc1) / (float)(K_SIZE * K_SIZE);
}

extern "C" void kernel_launch(void* const* d_in, const int* in_sizes, int n_in,
                              void* d_out, int out_size, void* d_ws, size_t ws_size,
                              hipStream_t stream) {
    const float* input = (const float*)d_in[0];
    const float* Lp    = (const float*)d_in[1];
    const float* wbuf  = (const float*)d_in[2];
    float* out = (float*)d_out;

    if (ws_size >= TBL_BYTES) {
        char* tbl = (char*)d_ws;
        const int pack_total = BATCH * ENT * ENT;              // 1,052,676
        pack_kernel<<<(pack_total + 255) / 256, 256, 0, stream>>>(input, tbl);
        fused_sample_kernel_f16<<<BATCH * HW / 256, 256, 0, stream>>>(tbl, Lp, wbuf, out);
    } else {
        fused_sample_kernel_f32<<<BATCH * HW / 256, 256, 0, stream>>>(input, Lp, wbuf, out);
    }
}

// Round 13
// 39.905 us; speedup vs baseline: 2.1938x; 1.0300x over previous
//
#include <hip/hip_runtime.h>
#include <math.h>

#define K_SIZE 5
#define EPS    1e-6f
#define EPS_L  1e-3f
#define EPS_W  1e-3f

#define BATCH 4
#define HGT   512
#define WID   512
#define HW    (HGT * WID)

// fp16 quad table: entry[b][ri][k] (ri,k in 0..512) =
//   { img[ri-1][k-1], img[ri-1][k], img[ri][k-1], img[ri][k] }  (OOB halves = 0)
// ri = y0+1, k = x0+1. One 8B load -> all 4 bilinear corners.
#define ENT        513
#define ROW_ENTRIES 520                         // pad for 64B-aligned rows
#define ROW_BYTES  (ROW_ENTRIES * 8)            // 4160 = 64*65
#define IMG_BYTES  (ENT * ROW_BYTES)            // 2,134,080
#define TBL_BYTES  ((size_t)BATCH * IMG_BYTES)  // ~8.5 MB

typedef int int32x4 __attribute__((ext_vector_type(4)));
typedef float floatx2 __attribute__((ext_vector_type(2)));
typedef _Float16 half4v __attribute__((ext_vector_type(4)));

// Raw buffer loads with hardware bounds check: OOB -> returns 0
__device__ float llvm_amdgcn_raw_buffer_load_fp32(int32x4 srsrc, int voffset,
                                                  int soffset, int aux)
    __asm("llvm.amdgcn.raw.buffer.load.f32");
__device__ floatx2 llvm_amdgcn_raw_buffer_load_2fp32(int32x4 srsrc, int voffset,
                                                     int soffset, int aux)
    __asm("llvm.amdgcn.raw.buffer.load.v2f32");

// ---------------- pack: f32 image -> fp16 quad table ----------------
__global__ __launch_bounds__(256) void pack_kernel(
    const float* __restrict__ input, char* __restrict__ tbl)
{
    const int t = blockIdx.x * blockDim.x + threadIdx.x;
    if (t >= BATCH * ENT * ENT) return;
    const int k  = t % ENT;
    const int ri = (t / ENT) % ENT;
    const int b  = t / (ENT * ENT);

    const float* __restrict__ img = input + (size_t)b * HW;

    const bool top = (ri >= 1), bot = (ri <= HGT - 1);
    const bool lef = (k  >= 1), rig = (k  <= WID - 1);
    const int yT = (ri - 1) << 9;
    const int yB = ri << 9;

    union { half4v h; floatx2 f; } cv;
    cv.h.x = (_Float16)((top && lef) ? img[yT + k - 1] : 0.0f);
    cv.h.y = (_Float16)((top && rig) ? img[yT + k]     : 0.0f);
    cv.h.z = (_Float16)((bot && lef) ? img[yB + k - 1] : 0.0f);
    cv.h.w = (_Float16)((bot && rig) ? img[yB + k]     : 0.0f);

    floatx2* dst = (floatx2*)(tbl + (size_t)b * IMG_BYTES + (size_t)ri * ROW_BYTES + ((size_t)k << 3));
    *dst = cv.f;
}

// ---------------- main fused kernel (fp16 quad-table gather) ----------------
__global__ __launch_bounds__(256) void fused_sample_kernel_f16(
    const char* __restrict__ tbl,      // packed table in ws
    const float* __restrict__ Lp,      // (B,H,W,3)
    const float* __restrict__ wbuf,    // (B,2,H,W)
    float* __restrict__ out)           // (B,1,H,W)
{
#pragma clang fp contract(off)
    const int idx = blockIdx.x * blockDim.x + threadIdx.x;

    const int b = blockIdx.x >> 10;     // 1024 blocks per image (uniform per block)
    const int p = idx & (HW - 1);
    const int y = p >> 9;
    const int x = p & (WID - 1);

    // SRD over this image's table: OOB rows -> outside num_records -> 0.
    union {
        struct { const void* base; unsigned num; unsigned cfg; } s;
        int32x4 v;
    } desc;
    desc.s.base = (const void*)(tbl + (size_t)b * IMG_BYTES);
    desc.s.num  = (unsigned)IMG_BYTES;
    desc.s.cfg  = 0x00020000u;
    const int32x4 rsrc = desc.v;

    // ---- per-pixel matrix (exactly mirrors numpy op order; amplified path) ----
    const size_t l_off = (size_t)idx * 3;
    const float L0 = Lp[l_off + 0];
    const float L1 = Lp[l_off + 1];
    const float L2 = Lp[l_off + 2];

    const float a  = fabsf(L0) + EPS_L;
    const float bb = L1;
    const float c  = fabsf(L2) + EPS_L;

    const float M00 = a * a;
    const float M01 = a * bb;
    const float M11 = (bb * bb) + (c * c);

    const float d00 = M00 + EPS;
    const float d11 = M11 + EPS;
    const float det = (d00 * d11) - (M01 * M01);
    const float I00 = d11 / det;          // IEEE f32 div, same as np
    const float I01 = (-M01) / det;
    const float I11 = d00 / det;

    const float wx = wbuf[(size_t)b * 2 * HW + p];
    const float wy = wbuf[(size_t)b * 2 * HW + HW + p];

    const float q    = (((I00 * wx) * wx) + (((2.0f * I01) * wx) * wy)) + ((I11 * wy) * wy);
    const float norm = sqrtf(q + EPS);

    const float e    = (float)exp((double)(-norm));   // correctly-rounded f32 exp
    const float sig  = 1.0f / (1.0f + e);
    const float tuned = ((sig - 0.5f) * 2.0f) * (1.0f - EPS_W);
    const float scale = tuned / (norm + EPS);         // IEEE div
    const float wtx = wx * scale;
    const float wty = wy * scale;

    // cos/sin of the FLOAT32-ROUNDED theta_k
    const float CT[K_SIZE] = { 1.0f,  0.30901696090f, -0.80901703575f, -0.80901693229f,  0.30901712828f };
    const float ST[K_SIZE] = { 0.0f,  0.95105652717f,  0.58778519534f, -0.58778533774f, -0.95105647279f };
    const float SV[K_SIZE] = { 0.2f, 0.4f, 0.6f, 0.8f, 1.0f };

    const float fy = (float)y;
    const float fx = (float)x;

    float acc0 = 0.0f;
    float acc1 = 0.0f;

    #pragma unroll
    for (int k = 0; k < K_SIZE; ++k) {
        const float ct = CT[k];
        const float st = ST[k];
        // amplified path: keep exact left-assoc, no contraction
        const float quad = (((M00 * ct) * ct) + (((2.0f * M01) * ct) * st)) + ((M11 * st) * st);
        const float F    = (sqrtf(quad) + (wtx * ct)) + (wty * st);
        const float Fe   = F + EPS;
        // downstream of cancellation: approx rcp safe (position error ~1e-7 rel)
        const float rFe  = __builtin_amdgcn_rcpf(Fe);
        const float yx   = ct * rFe;
        const float yy   = st * rFe;

        #pragma unroll
        for (int s = 0; s < K_SIZE; ++s) {
            const float sv = SV[s];
            const float gy = fmaf(sv, yy, fy);
            const float gx = fmaf(sv, yx, fx);

            const int   y0i = (int)floorf(gy);      // v_cvt_flr_i32_f32
            const int   x0i = (int)floorf(gx);
            const float wyf = __builtin_amdgcn_fractf(gy);
            const float wxf = __builtin_amdgcn_fractf(gx);

            // quad-entry coords: ri = y0+1 (row OOB -> SRD returns 0),
            // ke = clamp(x0+1) with zero weights on clamped x.
            const int ri = y0i + 1;
            const int ke = min(max(x0i + 1, 0), ENT - 1);
            const unsigned off = (unsigned)ri * (unsigned)ROW_BYTES + ((unsigned)ke << 3);

            const floatx2 pf = llvm_amdgcn_raw_buffer_load_2fp32(rsrc, (int)off, 0, 0);
            union { floatx2 f; half4v h; } cv;
            cv.f = pf;
            const float v00 = (float)cv.h.x;
            const float v01 = (float)cv.h.y;
            const float v10 = (float)cv.h.z;
            const float v11 = (float)cv.h.w;

            const bool vx0 = (unsigned)x0i < (unsigned)WID;
            const bool vx1 = (unsigned)(x0i + 1) < (unsigned)WID;
            const float zx0 = vx0 ? (1.0f - wxf) : 0.0f;
            const float zx1 = vx1 ? wxf : 0.0f;

            const float row0 = fmaf(v01, zx1, v00 * zx0);
            const float row1 = fmaf(v11, zx1, v10 * zx0);

            if (s & 1) {
                acc1 = fmaf(1.0f - wyf, row0, acc1);
                acc1 = fmaf(wyf,        row1, acc1);
            } else {
                acc0 = fmaf(1.0f - wyf, row0, acc0);
                acc0 = fmaf(wyf,        row1, acc0);
            }
        }
    }

    out[idx] = (acc0 + acc1) / (float)(K_SIZE * K_SIZE);
}

// ---------------- fallback: direct fp32 gather (proven, ~55us) ----------------
__global__ __launch_bounds__(256) void fused_sample_kernel_f32(
    const float* __restrict__ input,
    const float* __restrict__ Lp,
    const float* __restrict__ wbuf,
    float* __restrict__ out)
{
#pragma clang fp contract(off)
    const int idx = blockIdx.x * blockDim.x + threadIdx.x;
    const int b = blockIdx.x >> 10;
    const int p = idx & (HW - 1);
    const int y = p >> 9;
    const int x = p & (WID - 1);

    union {
        struct { const void* base; unsigned num; unsigned cfg; } s;
        int32x4 v;
    } desc;
    desc.s.base = (const void*)(input + (size_t)b * HW);
    desc.s.num  = HW * 4u;
    desc.s.cfg  = 0x00020000u;
    const int32x4 rsrc = desc.v;

    const size_t l_off = (size_t)idx * 3;
    const float L0 = Lp[l_off + 0];
    const float L1 = Lp[l_off + 1];
    const float L2 = Lp[l_off + 2];

    const float a  = fabsf(L0) + EPS_L;
    const float bb = L1;
    const float c  = fabsf(L2) + EPS_L;

    const float M00 = a * a;
    const float M01 = a * bb;
    const float M11 = (bb * bb) + (c * c);

    const float d00 = M00 + EPS;
    const float d11 = M11 + EPS;
    const float det = (d00 * d11) - (M01 * M01);
    const float I00 = d11 / det;
    const float I01 = (-M01) / det;
    const float I11 = d00 / det;

    const float wx = wbuf[(size_t)b * 2 * HW + p];
    const float wy = wbuf[(size_t)b * 2 * HW + HW + p];

    const float q    = (((I00 * wx) * wx) + (((2.0f * I01) * wx) * wy)) + ((I11 * wy) * wy);
    const float norm = sqrtf(q + EPS);
    const float e    = (float)exp((double)(-norm));
    const float sig  = 1.0f / (1.0f + e);
    const float tuned = ((sig - 0.5f) * 2.0f) * (1.0f - EPS_W);
    const float scale = tuned / (norm + EPS);
    const float wtx = wx * scale;
    const float wty = wy * scale;

    const float CT[K_SIZE] = { 1.0f,  0.30901696090f, -0.80901703575f, -0.80901693229f,  0.30901712828f };
    const float ST[K_SIZE] = { 0.0f,  0.95105652717f,  0.58778519534f, -0.58778533774f, -0.95105647279f };
    const float SV[K_SIZE] = { 0.2f, 0.4f, 0.6f, 0.8f, 1.0f };

    const float fy = (float)y;
    const float fx = (float)x;

    float acc0 = 0.0f;
    float acc1 = 0.0f;

    #pragma unroll
    for (int k = 0; k < K_SIZE; ++k) {
        const float ct = CT[k];
        const float st = ST[k];
        const float quad = (((M00 * ct) * ct) + (((2.0f * M01) * ct) * st)) + ((M11 * st) * st);
        const float F    = (sqrtf(quad) + (wtx * ct)) + (wty * st);
        const float Fe   = F + EPS;
        const float rFe  = __builtin_amdgcn_rcpf(Fe);
        const float yx   = ct * rFe;
        const float yy   = st * rFe;

        #pragma unroll
        for (int s = 0; s < K_SIZE; ++s) {
            const float sv = SV[s];
            const float gy = fmaf(sv, yy, fy);
            const float gx = fmaf(sv, yx, fx);

            const int   y0i = (int)floorf(gy);
            const int   x0i = (int)floorf(gx);
            const float wyf = __builtin_amdgcn_fractf(gy);
            const float wxf = __builtin_amdgcn_fractf(gx);

            const unsigned r0 = (unsigned)y0i << 11;
            const unsigned r1 = r0 + (WID * 4u);

            const int x1i = x0i + 1;
            const bool vx0 = (unsigned)x0i < (unsigned)WID;
            const bool vx1 = (unsigned)x1i < (unsigned)WID;
            const unsigned x0v = (unsigned)min(max(x0i, 0), WID - 1) << 2;
            const unsigned x1v = (unsigned)min(max(x1i, 0), WID - 1) << 2;

            const float v00 = llvm_amdgcn_raw_buffer_load_fp32(rsrc, (int)(r0 + x0v), 0, 0);
            const float v01 = llvm_amdgcn_raw_buffer_load_fp32(rsrc, (int)(r0 + x1v), 0, 0);
            const float v10 = llvm_amdgcn_raw_buffer_load_fp32(rsrc, (int)(r1 + x0v), 0, 0);
            const float v11 = llvm_amdgcn_raw_buffer_load_fp32(rsrc, (int)(r1 + x1v), 0, 0);

            const float zx0 = vx0 ? (1.0f - wxf) : 0.0f;
            const float zx1 = vx1 ? wxf : 0.0f;

            const float row0 = fmaf(v01, zx1, v00 * zx0);
            const float row1 = fmaf(v11, zx1, v10 * zx0);

            if (s & 1) {
                acc1 = fmaf(1.0f - wyf, row0, acc1);
                acc1 = fmaf(wyf,        row1, acc1);
            } else {
                acc0 = fmaf(1.0f - wyf, row0, acc0);
                acc0 = fmaf(wyf,        row1, acc0);
            }
        }
    }

    out[idx] = (acc0 + acc1) / (float)(K_SIZE * K_SIZE);
}

extern "C" void kernel_launch(void* const* d_in, const int* in_sizes, int n_in,
                              void* d_out, int out_size, void* d_ws, size_t ws_size,
                              hipStream_t stream) {
    const float* input = (const float*)d_in[0];
    const float* Lp    = (const float*)d_in[1];
    const float* wbuf  = (const float*)d_in[2];
    float* out = (float*)d_out;

    if (ws_size >= TBL_BYTES) {
        char* tbl = (char*)d_ws;
        const int pack_total = BATCH * ENT * ENT;              // 1,052,676
        pack_kernel<<<(pack_total + 255) / 256, 256, 0, stream>>>(input, tbl);
        fused_sample_kernel_f16<<<BATCH * HW / 256, 256, 0, stream>>>(tbl, Lp, wbuf, out);
    } else {
        fused_sample_kernel_f32<<<BATCH * HW / 256, 256, 0, stream>>>(input, Lp, wbuf, out);
    }
}